// Round 1
// baseline (2718.062 us; speedup 1.0000x reference)
//
#include <hip/hip_runtime.h>

#define THRESH 0.1f

// ---------------------------------------------------------------------------
// Weight norm: w[row,:] = g[row] * v[row,:] / ||v[row,:]||   (one wave / row)
// ---------------------------------------------------------------------------
__global__ void wnorm_kernel(const float* __restrict__ v, const float* __restrict__ g,
                             float* __restrict__ w, int fanin) {
    int row = blockIdx.x;
    const float* vr = v + (size_t)row * fanin;
    float ss = 0.f;
    for (int i = threadIdx.x; i < fanin; i += 64) { float x = vr[i]; ss = fmaf(x, x, ss); }
    #pragma unroll
    for (int off = 32; off > 0; off >>= 1) ss += __shfl_down(ss, off);
    ss = __shfl(ss, 0);
    float scale = g[row] / sqrtf(ss);
    float* wr = w + (size_t)row * fanin;
    for (int i = threadIdx.x; i < fanin; i += 64) wr[i] = vr[i] * scale;
}

// ---------------------------------------------------------------------------
// Fused 3x3 SAME conv + IAF (integrate & fire, membrane-subtract) + 2x2 avgpool.
// in : (B*T, CIN, H, H)   previous layer pooled spikes (or network input)
// w  : (COUT, CIN, 3, 3)  normalized weights
// out: (B*T, COUT, H/2, H/2)
// One thread owns a 2x2 conv-pixel block (4 IAF states) and loops t=0..T-1.
// ---------------------------------------------------------------------------
template<int CIN, int H, int COUT>
__launch_bounds__(256)
__global__ void conv_iaf_pool(const float* __restrict__ in, const float* __restrict__ w,
                              float* __restrict__ out, int B, int T) {
    constexpr int Hp = H / 2;
    constexpr int PP = Hp * Hp;                 // pooled pixels per (b, c)
    constexpr int CPB = (PP >= 256) ? 1 : (256 / PP);   // c_outs covered by a block
    __shared__ float lw[CPB * CIN * 9];

    const int n  = blockIdx.x * 256 + threadIdx.x;      // grid sized exactly
    const int xp = n % Hp;
    const int yp = (n / Hp) % Hp;
    const int c  = (n / PP) % COUT;
    const int b  = n / (PP * COUT);
    const int c0 = ((blockIdx.x * 256) / PP) % COUT;    // first c_out in this block

    for (int i = threadIdx.x; i < CPB * CIN * 9; i += 256)
        lw[i] = w[(size_t)c0 * CIN * 9 + i];
    __syncthreads();

    const float* wc0 = lw + (c - c0) * (CIN * 9);
    const int y0 = 2 * yp, x0 = 2 * xp;

    float v0 = 0.f, v1 = 0.f, v2 = 0.f, v3 = 0.f;       // membrane potentials

    for (int t = 0; t < T; ++t) {
        const float* inb = in + (size_t)(b * T + t) * (CIN * H * H);
        float a0 = 0.f, a1 = 0.f, a2 = 0.f, a3 = 0.f;
        for (int ci = 0; ci < CIN; ++ci) {
            const float* ib = inb + ci * (H * H);
            float p[16];                                 // 4x4 input patch (with padding)
            #pragma unroll
            for (int r = 0; r < 4; ++r) {
                const int y = y0 - 1 + r;
                const bool yok = ((unsigned)y < (unsigned)H);
                #pragma unroll
                for (int cc = 0; cc < 4; ++cc) {
                    const int x = x0 - 1 + cc;
                    const bool ok = yok && ((unsigned)x < (unsigned)H);
                    p[r * 4 + cc] = ok ? ib[y * H + x] : 0.f;
                }
            }
            const float* wc = wc0 + ci * 9;
            #pragma unroll
            for (int ky = 0; ky < 3; ++ky) {
                #pragma unroll
                for (int kx = 0; kx < 3; ++kx) {
                    const float wv = wc[ky * 3 + kx];
                    a0 = fmaf(p[ky * 4 + kx],           wv, a0);
                    a1 = fmaf(p[ky * 4 + kx + 1],       wv, a1);
                    a2 = fmaf(p[(ky + 1) * 4 + kx],     wv, a2);
                    a3 = fmaf(p[(ky + 1) * 4 + kx + 1], wv, a3);
                }
            }
        }
        v0 += a0; v1 += a1; v2 += a2; v3 += a3;
        const float s0 = (v0 >= THRESH) ? 1.f : 0.f;
        const float s1 = (v1 >= THRESH) ? 1.f : 0.f;
        const float s2 = (v2 >= THRESH) ? 1.f : 0.f;
        const float s3 = (v3 >= THRESH) ? 1.f : 0.f;
        v0 -= THRESH * s0; v1 -= THRESH * s1; v2 -= THRESH * s2; v3 -= THRESH * s3;
        out[((size_t)(b * T + t) * COUT + c) * PP + yp * Hp + xp] =
            0.25f * (s0 + s1 + s2 + s3);
    }
}

// ---------------------------------------------------------------------------
// Linear: out (1600, 11) = h (1600, 1024) @ w^T (11, 1024)
// One block per row n; row staged in LDS; threads 0..10 do the dots.
// ---------------------------------------------------------------------------
__global__ void linear_kernel(const float* __restrict__ h, const float* __restrict__ w,
                              float* __restrict__ out) {
    __shared__ float hs[1024];
    const int n = blockIdx.x;
    for (int i = threadIdx.x; i < 1024; i += blockDim.x)
        hs[i] = h[(size_t)n * 1024 + i];
    __syncthreads();
    const int j = threadIdx.x;
    if (j < 11) {
        float acc = 0.f;
        const float* wr = w + (size_t)j * 1024;
        for (int k = 0; k < 1024; ++k) acc = fmaf(hs[k], wr[k], acc);
        out[(size_t)n * 11 + j] = acc;
    }
}

// ---------------------------------------------------------------------------
extern "C" void kernel_launch(void* const* d_in, const int* in_sizes, int n_in,
                              void* d_out, int out_size, void* d_ws, size_t ws_size,
                              hipStream_t stream) {
    const int B = 32, T = 50;

    const float* x   = (const float*)d_in[0];
    const float* c0v = (const float*)d_in[1];
    const float* c0g = (const float*)d_in[2];
    const float* c1v = (const float*)d_in[3];
    const float* c1g = (const float*)d_in[4];
    const float* c2v = (const float*)d_in[5];
    const float* c2g = (const float*)d_in[6];
    const float* c3v = (const float*)d_in[7];
    const float* c3g = (const float*)d_in[8];
    const float* lv  = (const float*)d_in[9];
    const float* lg  = (const float*)d_in[10];
    float* out = (float*)d_out;

    // Workspace layout (floats)
    float* ws = (float*)d_ws;
    float* w0 = ws;                    // 8*2*9     = 144
    float* w1 = w0 + 144;              // 16*8*9    = 1152
    float* w2 = w1 + 1152;             // 32*16*9   = 4608
    float* w3 = w2 + 4608;             // 64*32*9   = 18432
    float* wl = w3 + 18432;            // 11*1024   = 11264
    float* bufA = ws + 40960;                  // L0 out: 1600*8*32*32  = 13,107,200
    float* bufB = bufA + (size_t)13107200;     // L1 out: 1600*16*16*16 =  6,553,600
    // L2 out (3,276,800) reuses bufA; L3 out (1,638,400) reuses bufB.

    // Normalized weights
    wnorm_kernel<<<8,  64, 0, stream>>>(c0v, c0g, w0, 2 * 9);
    wnorm_kernel<<<16, 64, 0, stream>>>(c1v, c1g, w1, 8 * 9);
    wnorm_kernel<<<32, 64, 0, stream>>>(c2v, c2g, w2, 16 * 9);
    wnorm_kernel<<<64, 64, 0, stream>>>(c3v, c3g, w3, 32 * 9);
    wnorm_kernel<<<11, 64, 0, stream>>>(lv,  lg,  wl, 1024);

    // Layer 0: (BT,2,64,64) -> (BT,8,32,32)   N = 32*8*1024 = 262144
    conv_iaf_pool<2, 64, 8><<<262144 / 256, 256, 0, stream>>>(x, w0, bufA, B, T);
    // Layer 1: (BT,8,32,32) -> (BT,16,16,16)  N = 32*16*256 = 131072
    conv_iaf_pool<8, 32, 16><<<131072 / 256, 256, 0, stream>>>(bufA, w1, bufB, B, T);
    // Layer 2: (BT,16,16,16) -> (BT,32,8,8)   N = 32*32*64  = 65536
    conv_iaf_pool<16, 16, 32><<<65536 / 256, 256, 0, stream>>>(bufB, w2, bufA, B, T);
    // Layer 3: (BT,32,8,8) -> (BT,64,4,4)     N = 32*64*16  = 32768
    conv_iaf_pool<32, 8, 64><<<32768 / 256, 256, 0, stream>>>(bufA, w3, bufB, B, T);

    // Linear: (1600,1024) @ (11,1024)^T -> (1600,11)
    linear_kernel<<<B * T, 256, 0, stream>>>(bufB, wl, out);
}